// Round 6
// baseline (4641.472 us; speedup 1.0000x reference)
//
#include <hip/hip_runtime.h>
#include <math.h>

#define NB 256
#define TT 128
#define DD 512
#define HH 1024
#define KHX 1536    // 512 (x) + 1024 (h)
#define KFB 2560
#define BK 128
#define NBLK4 256

typedef _Float16 half_t;
typedef _Float16 half8 __attribute__((ext_vector_type(8)));
typedef _Float16 half4v __attribute__((ext_vector_type(4)));
typedef _Float16 half2v __attribute__((ext_vector_type(2)));
typedef float f32x4 __attribute__((ext_vector_type(4)));

// ========================= PRE-KERNELS =========================

// ---- generic fp32 [K][4096] -> fp16 [4096][kstride] transpose ----
__global__ __launch_bounds__(256) void k_trans(const float* __restrict__ src,
        half_t* __restrict__ dst, int kstride, int koff, int nkt) {
    __shared__ half_t tile[64][65];
    int bk = blockIdx.x % nkt;
    int bn = blockIdx.x / nkt;
    int k0 = bk * 64, n0 = bn * 64;
    #pragma unroll
    for (int i = 0; i < 16; ++i) {
        int idx = i * 256 + threadIdx.x;
        int r = idx >> 6, c = idx & 63;
        tile[c][r] = (half_t)src[(size_t)(k0 + r) * 4096 + n0 + c];
    }
    __syncthreads();
    #pragma unroll
    for (int i = 0; i < 16; ++i) {
        int idx = i * 256 + threadIdx.x;
        int r = idx >> 6, c = idx & 63;
        dst[(size_t)(n0 + r) * kstride + koff + k0 + c] = tile[r][c];
    }
}

// ---- x fp32 -> fp16 ----
__global__ __launch_bounds__(256) void k_convX(const float* __restrict__ x,
        half_t* __restrict__ x16) {
    size_t base = ((size_t)blockIdx.x * 256 + threadIdx.x) * 32;
    #pragma unroll
    for (int u = 0; u < 4; ++u) {
        float4 a = ((const float4*)(x + base))[2 * u];
        float4 c = ((const float4*)(x + base))[2 * u + 1];
        half8 p;
        p[0] = (half_t)a.x; p[1] = (half_t)a.y; p[2] = (half_t)a.z; p[3] = (half_t)a.w;
        p[4] = (half_t)c.x; p[5] = (half_t)c.y; p[6] = (half_t)c.z; p[7] = (half_t)c.w;
        ((half8*)(x16 + base))[u] = p;
    }
}

// ---- A conversions + h0/c0 (fast path: no score init here) ----
__global__ __launch_bounds__(256) void k_convA2(const float* __restrict__ A,
        half_t* __restrict__ A16, half_t* __restrict__ AsT,
        float* __restrict__ cbuf, half_t* __restrict__ h16) {
    int n = blockIdx.x, tid = threadIdx.x;
    #pragma unroll
    for (int r = 0; r < 4; ++r) {
        int h = tid + r * 256;
        const float4* ap = (const float4*)(A + ((size_t)n * HH + h) * 16);
        float4 v0 = ap[0], v1 = ap[1], v2 = ap[2], v3 = ap[3];
        float a[16];
        a[0]=v0.x; a[1]=v0.y; a[2] =v0.z; a[3] =v0.w;
        a[4]=v1.x; a[5]=v1.y; a[6] =v1.z; a[7] =v1.w;
        a[8]=v2.x; a[9]=v2.y; a[10]=v2.z; a[11]=v2.w;
        a[12]=v3.x; a[13]=v3.y; a[14]=v3.z; a[15]=v3.w;
        float hv = 0.f;
        #pragma unroll
        for (int s = 0; s < 16; ++s) hv += a[s];
        hv *= (1.f / 16.f);
        size_t ci = (size_t)n * HH + h;
        cbuf[ci] = hv;
        h16[ci] = (half_t)hv;
        half8 q0, q1;
        #pragma unroll
        for (int s = 0; s < 8; ++s) { q0[s] = (half_t)a[s]; q1[s] = (half_t)a[s + 8]; }
        *(half8*)(A16 + ci * 16) = q0;
        *(half8*)(A16 + ci * 16 + 8) = q1;
        #pragma unroll
        for (int s = 0; s < 16; ++s)
            AsT[(size_t)n * 16 * HH + (size_t)s * HH + h] = (half_t)a[s];
    }
}

// ---- initial scores (slice 0) + zero the 8-slice triple buffers ----
__global__ __launch_bounds__(256) void k_initsc(const half_t* __restrict__ h16,
        const half_t* __restrict__ A16,
        float* __restrict__ sc0, float* __restrict__ sc1, float* __restrict__ sc2) {
    __shared__ float sred[4][16];
    int n = blockIdx.x, tid = threadIdx.x;
    float ps[16];
    #pragma unroll
    for (int s = 0; s < 16; ++s) ps[s] = 0.f;
    #pragma unroll
    for (int r = 0; r < 4; ++r) {
        int h = tid + r * 256;
        size_t ci = (size_t)n * HH + h;
        float hv = (float)h16[ci];
        const half8* ap = (const half8*)(A16 + ci * 16);
        half8 a0 = ap[0], a1 = ap[1];
        #pragma unroll
        for (int s = 0; s < 8; ++s) {
            ps[s]     += hv * (float)a0[s];
            ps[s + 8] += hv * (float)a1[s];
        }
    }
    #pragma unroll
    for (int off = 32; off; off >>= 1)
        #pragma unroll
        for (int s = 0; s < 16; ++s) ps[s] += __shfl_xor(ps[s], off, 64);
    int wave = tid >> 6;
    if ((tid & 63) == 0)
        #pragma unroll
        for (int s = 0; s < 16; ++s) sred[wave][s] = ps[s];
    __syncthreads();
    if (tid < 16)
        sc0[(size_t)n * 16 + tid] =
            sred[0][tid] + sred[1][tid] + sred[2][tid] + sred[3][tid];
    if (tid < 112) {
        int x = 1 + tid / 16, s = tid % 16;
        sc0[((size_t)x * 256 + n) * 16 + s] = 0.f;
    }
    if (tid < 128) {
        int x = tid / 16, s = tid % 16;
        sc1[((size_t)x * 256 + n) * 16 + s] = 0.f;
        sc2[((size_t)x * 256 + n) * 16 + s] = 0.f;
    }
}

// ---- G[n][g*1024+j][s] = sum_h A[n,h,s] * Wattn[h,g*1024+j], fp16 out ----
__global__ __launch_bounds__(256) void k_gemm_G(const half_t* __restrict__ AsT,
        const half_t* __restrict__ WaT, half_t* __restrict__ G16) {
    __shared__ half_t sAs[16][BK + 8];
    __shared__ half_t sB[4][16][BK + 8];
    int bid = blockIdx.x;
    int n = bid >> 6, jt = bid & 63;
    int j0 = jt * 16;
    int tid = threadIdx.x, wv = tid >> 6, lane = tid & 63;
    f32x4 acc = {};
    int srB = tid >> 2, scB = (tid & 3) * 32;
    int gB = srB >> 4, jcB = srB & 15;
    for (int it = 0; it < HH / BK; ++it) {
        int k0 = it * BK;
        if (tid < 128) {
            int r = tid >> 3, c = (tid & 7) * 16;
            const uint4* sp = (const uint4*)(AsT + (size_t)n * 16 * HH + (size_t)r * HH + k0 + c);
            uint4 u0 = sp[0], u1 = sp[1];
            *(uint4*)&sAs[r][c] = u0;
            *(uint4*)&sAs[r][c + 8] = u1;
        }
        {
            const half_t* src = WaT + ((size_t)(gB * HH + j0 + jcB)) * HH + k0 + scB;
            uint4 u0 = ((const uint4*)src)[0];
            uint4 u1 = ((const uint4*)src)[1];
            uint4 u2 = ((const uint4*)src)[2];
            uint4 u3 = ((const uint4*)src)[3];
            *((uint4*)&sB[gB][jcB][scB])      = u0;
            *((uint4*)&sB[gB][jcB][scB + 8])  = u1;
            *((uint4*)&sB[gB][jcB][scB + 16]) = u2;
            *((uint4*)&sB[gB][jcB][scB + 24]) = u3;
        }
        __syncthreads();
        int row16 = lane & 15, kg = lane >> 4;
        #pragma unroll
        for (int kc = 0; kc < BK / 32; ++kc) {
            half8 bf = *(const half8*)&sB[wv][row16][kc * 32 + kg * 8];
            half8 af = *(const half8*)&sAs[row16][kc * 32 + kg * 8];
            acc = __builtin_amdgcn_mfma_f32_16x16x32_f16(af, bf, acc, 0, 0, 0);
        }
        __syncthreads();
    }
    int col = lane & 15, rbase = (lane >> 4) * 4;
    size_t jf = (size_t)wv * HH + j0 + col;
    half4v o;
    o[0] = (half_t)acc[0]; o[1] = (half_t)acc[1];
    o[2] = (half_t)acc[2]; o[3] = (half_t)acc[3];
    *(half4v*)(G16 + ((size_t)n * 4096 + jf) * 16 + rbase) = o;
}

// ---- XW = x @ Wx, written as per-(t,jb,mhalf) slabs, LDS-staged epilogue ----
__global__ __launch_bounds__(256) void k_gemm_XW(const half_t* __restrict__ x16,
        const half_t* __restrict__ WhxT, half_t* __restrict__ XW16) {
    __shared__ half_t sA[128][72];
    __shared__ half_t sB[64][72];
    int bid = blockIdx.x;
    int bm = bid & 255;        // 32768/128
    int bj = bid >> 8;         // 4096/64
    int row0 = bm * 128;
    int col0 = bj * 64;
    int tid = threadIdx.x, wv = tid >> 6, lane = tid & 63;
    int la = lane & 15, kg = lane >> 4;
    int mh = wv & 1, jh = wv >> 1;
    f32x4 acc[4][2] = {};
    int srA = tid >> 1, scA = (tid & 1) * 32;
    int srB = tid >> 2, scB = (tid & 3) * 16;
    for (int c = 0; c < 8; ++c) {
        {
            const uint4* sp = (const uint4*)(x16 + (size_t)(row0 + srA) * DD + c * 64 + scA);
            uint4 u0 = sp[0], u1 = sp[1];
            *(uint4*)&sA[srA][scA] = u0;
            *(uint4*)&sA[srA][scA + 8] = u1;
        }
        {
            const uint4* sp = (const uint4*)(WhxT + (size_t)(col0 + srB) * KHX + c * 64 + scB);
            *(uint4*)&sB[srB][scB] = sp[0];
        }
        __syncthreads();
        #pragma unroll
        for (int ks = 0; ks < 2; ++ks) {
            half8 b0 = *(const half8*)&sB[jh * 32 + la][ks * 32 + kg * 8];
            half8 b1 = *(const half8*)&sB[jh * 32 + 16 + la][ks * 32 + kg * 8];
            #pragma unroll
            for (int m = 0; m < 4; ++m) {
                half8 af = *(const half8*)&sA[mh * 64 + m * 16 + la][ks * 32 + kg * 8];
                acc[m][0] = __builtin_amdgcn_mfma_f32_16x16x32_f16(af, b0, acc[m][0], 0, 0, 0);
                acc[m][1] = __builtin_amdgcn_mfma_f32_16x16x32_f16(af, b1, acc[m][1], 0, 0, 0);
            }
        }
        __syncthreads();
    }
    // stage C tile (128 x 64 halfs) in LDS, then 16B stores to slabs
    __syncthreads();
    half_t (*Cl)[72] = sA;
    #pragma unroll
    for (int m = 0; m < 4; ++m)
        #pragma unroll
        for (int jt = 0; jt < 2; ++jt)
            #pragma unroll
            for (int q = 0; q < 4; ++q) {
                int rl = mh * 64 + m * 16 + kg * 4 + q;
                int cl = jh * 32 + jt * 16 + la;
                Cl[rl][cl] = (half_t)acc[m][jt][q];
            }
    __syncthreads();
    int g = col0 >> 10;
    #pragma unroll
    for (int i = 0; i < 4; ++i) {
        int idx = tid + i * 256;           // 0..1023
        int rl = idx >> 3, grp = idx & 7;
        int R = row0 + rl;
        int t = R & 127, nn = R >> 7;
        int mh2 = nn >> 7, nl2 = nn & 127;
        int jb2 = ((col0 & 1023) >> 3) + grp;
        size_t dst = ((((size_t)t * 128 + jb2) * 2 + mh2) * 128 + nl2) * 32 + g * 8;
        *(half8*)(XW16 + dst) = *(const half8*)&Cl[rl][grp * 8];
    }
}

// ========================= PERSISTENT STEP KERNEL v4 =========================

struct StepLds4 {
    half_t W[32][1028];               // 65,792 B, resident, pad -> conflict-free
    union {
        half_t H[128][260];           // 66,560 B chunk buffer (pad 4)
        float sm[4][128][16];         // 32,768 B (softmax slice combine)
        struct {
            float pe[128][33];        // 16,896 B
            float pad[896];
            float ps[2][128][18];     // 18,432 B
        } e;
    } u;
};

__device__ __forceinline__ void grid_sync4(int* cnt, volatile int* flag, int inst) {
    __syncthreads();
    if (threadIdx.x == 0) {
        __threadfence();
        int prev = __hip_atomic_fetch_add(cnt, 1, __ATOMIC_RELAXED,
                                          __HIP_MEMORY_SCOPE_AGENT);
        if (prev == NBLK4 * (inst + 1) - 1) {
            __hip_atomic_store((int*)flag, inst + 1, __ATOMIC_RELAXED,
                               __HIP_MEMORY_SCOPE_AGENT);
        } else {
            int guard = 0;
            while (__hip_atomic_load((int*)flag, __ATOMIC_RELAXED,
                                     __HIP_MEMORY_SCOPE_AGENT) < inst + 1) {
                __builtin_amdgcn_s_sleep(2);
                if (++guard > (1 << 24)) break;
            }
        }
        __threadfence();
    }
    __syncthreads();
}

__global__ __launch_bounds__(512, 1) void k_steps4(
        const half_t* __restrict__ XW16, half_t* __restrict__ h16A,
        half_t* __restrict__ h16B, const half_t* __restrict__ WhxT,
        const half_t* __restrict__ A16, const half_t* __restrict__ G16,
        const float* __restrict__ b, const float* __restrict__ cbuf,
        float* __restrict__ sc0, float* __restrict__ sc1, float* __restrict__ sc2,
        float* __restrict__ out, int* __restrict__ bar) {
    __shared__ StepLds4 L;
    int bid = blockIdx.x;
    int mhalf = bid & 1, jb = bid >> 1;   // jb 0..127
    int n0 = mhalf * 128;
    int tid = threadIdx.x;
    int wv = tid >> 6, lane = tid & 63;
    int la = lane & 15, kg = lane >> 4;
    int srow = tid >> 2, sseg = tid & 3;  // staging: row, 64-half segment
    int slice = bid & 7;
    int* cnt = bar;
    volatile int* flag = (volatile int*)(bar + 32);

    // ---- W_h (32 rows x 1024 k) into LDS once ----
    {
        int wr = tid >> 4, seg = tid & 15;
        const half_t* wsrc = WhxT + (size_t)((wr >> 3) * HH + jb * 8 + (wr & 7)) * KHX
                           + DD + seg * 64;
        #pragma unroll
        for (int i = 0; i < 8; ++i)
            *(uint4*)&L.W[wr][seg * 64 + i * 8] = ((const uint4*)wsrc)[i];
    }

    // ---- pinned invariants: thread owns (n, 2 j-cols) ----
    int n_l = tid & 127, jg2 = tid >> 7;  // jg2 0..3
    int n = n0 + n_l;
    int jbase = jb * 8 + jg2 * 2;
    half8 gq[4][4];
    #pragma unroll
    for (int g = 0; g < 4; ++g) {
        const half8* gsrc = (const half8*)(G16 + ((size_t)n * 4096 + g * HH + jbase) * 16);
        #pragma unroll
        for (int i = 0; i < 4; ++i) gq[g][i] = gsrc[i];
    }
    half8 aq[4];
    {
        const half8* asrc = (const half8*)(A16 + ((size_t)n * HH + jbase) * 16);
        #pragma unroll
        for (int i = 0; i < 4; ++i) aq[i] = asrc[i];
    }
    float bb[4][2];
    #pragma unroll
    for (int g = 0; g < 4; ++g) {
        bb[g][0] = b[g * HH + jbase];
        bb[g][1] = b[g * HH + jbase + 1];
    }
    float creg[2];
    creg[0] = cbuf[(size_t)n * HH + jbase];
    creg[1] = cbuf[(size_t)n * HH + jbase + 1];

    float* scC = sc0; float* scN = sc1; float* scZ = sc2;
    half_t* h16c = h16A;
    half_t* h16n = h16B;

    half2v xwv[4];
    {
        const half_t* xwp = XW16 + (((size_t)jb * 2 + mhalf) * 128 + n_l) * 32;
        #pragma unroll
        for (int g = 0; g < 4; ++g) xwv[g] = *(const half2v*)(xwp + g * 8 + jg2 * 2);
    }

    for (int t = 0; t < TT; ++t) {
        if (bid < 64) ((float*)scZ)[bid * 512 + tid] = 0.f;

        // ---- softmax: each dup thread sums 2 slices, combine 4 via LDS ----
        {
            const float* p0 = scC + ((size_t)(jg2 * 2) * 256 + n) * 16;
            const float* p1 = scC + ((size_t)(jg2 * 2 + 1) * 256 + n) * 16;
            #pragma unroll
            for (int i = 0; i < 4; ++i) {
                float4 a = ((const float4*)p0)[i];
                float4 c = ((const float4*)p1)[i];
                float4 o;
                o.x = a.x + c.x; o.y = a.y + c.y; o.z = a.z + c.z; o.w = a.w + c.w;
                *(float4*)&L.u.sm[jg2][n_l][4 * i] = o;
            }
        }
        __syncthreads();
        float w16[16];
        {
            float sc[16];
            #pragma unroll
            for (int i = 0; i < 4; ++i) {
                float4 q0 = *(const float4*)&L.u.sm[0][n_l][4 * i];
                float4 q1 = *(const float4*)&L.u.sm[1][n_l][4 * i];
                float4 q2 = *(const float4*)&L.u.sm[2][n_l][4 * i];
                float4 q3 = *(const float4*)&L.u.sm[3][n_l][4 * i];
                sc[4 * i + 0] = q0.x + q1.x + q2.x + q3.x;
                sc[4 * i + 1] = q0.y + q1.y + q2.y + q3.y;
                sc[4 * i + 2] = q0.z + q1.z + q2.z + q3.z;
                sc[4 * i + 3] = q0.w + q1.w + q2.w + q3.w;
            }
            float m = -1e30f;
            #pragma unroll
            for (int s = 0; s < 16; ++s) { sc[s] *= 0.03125f; m = fmaxf(m, sc[s]); }
            float den = 0.f;
            #pragma unroll
            for (int s = 0; s < 16; ++s) { sc[s] = expf(sc[s] - m); den += sc[s]; }
            float inv = 1.f / den;
            #pragma unroll
            for (int s = 0; s < 16; ++s) w16[s] = sc[s] * inv;
        }

        // ---- GEMM: h @ Wh, 4 chunks of K=256, single buffer + reg prefetch ----
        f32x4 acc0 = {}, acc1 = {};
        uint4 r[8];
        {
            const half_t* src = h16c + (size_t)(n0 + srow) * HH + sseg * 64;
            #pragma unroll
            for (int i = 0; i < 8; ++i) r[i] = ((const uint4*)src)[i];
        }
        __syncthreads();                       // sm reads done; H free
        #pragma unroll 1
        for (int c = 0; c < 4; ++c) {
            #pragma unroll
            for (int i = 0; i < 8; ++i)
                *(uint4*)&L.u.H[srow][sseg * 64 + i * 8] = r[i];
            __syncthreads();
            if (c + 1 < 4) {
                const half_t* src = h16c + (size_t)(n0 + srow) * HH + (c + 1) * 256 + sseg * 64;
                #pragma unroll
                for (int i = 0; i < 8; ++i) r[i] = ((const uint4*)src)[i];
            }
            #pragma unroll
            for (int ks = 0; ks < 8; ++ks) {
                half8 af = *(const half8*)&L.u.H[wv * 16 + la][ks * 32 + kg * 8];
                half8 b0 = *(const half8*)&L.W[la][c * 256 + ks * 32 + kg * 8];
                half8 b1 = *(const half8*)&L.W[16 + la][c * 256 + ks * 32 + kg * 8];
                acc0 = __builtin_amdgcn_mfma_f32_16x16x32_f16(af, b0, acc0, 0, 0, 0);
                acc1 = __builtin_amdgcn_mfma_f32_16x16x32_f16(af, b1, acc1, 0, 0, 0);
            }
            __syncthreads();
        }

        // ---- C-frag exchange via pe ----
        #pragma unroll
        for (int q = 0; q < 4; ++q) {
            L.u.e.pe[wv * 16 + kg * 4 + q][la]      = acc0[q];
            L.u.e.pe[wv * 16 + kg * 4 + q][16 + la] = acc1[q];
        }
        __syncthreads();

        // ---- epilogue: gates + state + h + score partials ----
        float v[4][2];
        #pragma unroll
        for (int g = 0; g < 4; ++g) {
            #pragma unroll
            for (int jj = 0; jj < 2; ++jj) {
                float a0 = 0.f;
                #pragma unroll
                for (int s = 0; s < 16; ++s)
                    a0 += w16[s] * (float)gq[g][jj * 2 + (s >> 3)][s & 7];
                v[g][jj] = L.u.e.pe[n_l][g * 8 + jg2 * 2 + jj] + bb[g][jj]
                         + (float)xwv[g][jj] + a0;
            }
        }
        float hv[2];
        #pragma unroll
        for (int jj = 0; jj < 2; ++jj) {
            float ig = 1.f / (1.f + expf(-v[0][jj]));
            float fg = 1.f / (1.f + expf(-v[1][jj]));
            float og = 1.f / (1.f + expf(-v[2][jj]));
            float gg = tanhf(v[3][jj]);
            float cn = fg * creg[jj] + ig * gg;
            creg[jj] = cn;
            hv[jj] = og * tanhf(cn);
        }
        {
            float2 o2; o2.x = hv[0]; o2.y = hv[1];
            *(float2*)(out + ((size_t)n * TT + t) * HH + jbase) = o2;
            half2v h2; h2[0] = (half_t)hv[0]; h2[1] = (half_t)hv[1];
            *(half2v*)(h16n + (size_t)n * HH + jbase) = h2;
        }
        float p[16];
        #pragma unroll
        for (int s = 0; s < 16; ++s)
            p[s] = hv[0] * (float)aq[s >> 3][s & 7]
                 + hv[1] * (float)aq[2 + (s >> 3)][s & 7];
        int pair = jg2 >> 1;
        if ((jg2 & 1) == 0) {
            #pragma unroll
            for (int s = 0; s < 16; ++s) L.u.e.ps[pair][n_l][s] = p[s];
        }
        __syncthreads();
        if ((jg2 & 1) == 1) {
            #pragma unroll
            for (int s = 0; s < 16; ++s) L.u.e.ps[pair][n_l][s] += p[s];
        }
        __syncthreads();
        #pragma unroll
        for (int i = 0; i < 4; ++i) {
            int slot = tid * 4 + i;
            int nn = slot >> 4, s = slot & 15;
            atomicAdd(scN + ((size_t)slice * 256 + n0 + nn) * 16 + s,
                      L.u.e.ps[0][nn][s] + L.u.e.ps[1][nn][s]);
        }

        // ---- XW prefetch for t+1 hidden under the grid sync ----
        if (t + 1 < TT) {
            half2v xwn[4];
            const half_t* xwp = XW16 + ((((size_t)(t + 1) * 128 + jb) * 2 + mhalf) * 128 + n_l) * 32;
            #pragma unroll
            for (int g = 0; g < 4; ++g) xwn[g] = *(const half2v*)(xwp + g * 8 + jg2 * 2);
            grid_sync4(cnt, flag, t);
            #pragma unroll
            for (int g = 0; g < 4; ++g) xwv[g] = xwn[g];
        }
        float* tmp = scC; scC = scN; scN = scZ; scZ = tmp;
        half_t* th = h16c; h16c = h16n; h16n = th;
    }
}

// ========================= MID PATH (round-2, proven) =========================

__global__ __launch_bounds__(256) void k_convA(const float* __restrict__ A,
        half_t* __restrict__ A16, half_t* __restrict__ AsT,
        float* __restrict__ cbuf, half_t* __restrict__ h16,
        float* __restrict__ sc0, float* __restrict__ sc1, float* __restrict__ sc2) {
    __shared__ float sred[4][16];
    int n = blockIdx.x, tid = threadIdx.x;
    float ps[16];
    #pragma unroll
    for (int s = 0; s < 16; ++s) ps[s] = 0.f;
    #pragma unroll
    for (int r = 0; r < 4; ++r) {
        int h = tid + r * 256;
        const float4* ap = (const float4*)(A + ((size_t)n * HH + h) * 16);
        float4 v0 = ap[0], v1 = ap[1], v2 = ap[2], v3 = ap[3];
        float a[16];
        a[0]=v0.x; a[1]=v0.y; a[2] =v0.z; a[3] =v0.w;
        a[4]=v1.x; a[5]=v1.y; a[6] =v1.z; a[7] =v1.w;
        a[8]=v2.x; a[9]=v2.y; a[10]=v2.z; a[11]=v2.w;
        a[12]=v3.x; a[13]=v3.y; a[14]=v3.z; a[15]=v3.w;
        float hv = 0.f;
        #pragma unroll
        for (int s = 0; s < 16; ++s) hv += a[s];
        hv *= (1.f / 16.f);
        size_t ci = (size_t)n * HH + h;
        cbuf[ci] = hv;
        h16[ci] = (half_t)hv;
        half8 q0, q1;
        #pragma unroll
        for (int s = 0; s < 8; ++s) { q0[s] = (half_t)a[s]; q1[s] = (half_t)a[s + 8]; }
        *(half8*)(A16 + ci * 16) = q0;
        *(half8*)(A16 + ci * 16 + 8) = q1;
        #pragma unroll
        for (int s = 0; s < 16; ++s)
            AsT[(size_t)n * 16 * HH + (size_t)s * HH + h] = (half_t)a[s];
        #pragma unroll
        for (int s = 0; s < 16; ++s) ps[s] += hv * a[s];
    }
    #pragma unroll
    for (int off = 32; off; off >>= 1)
        #pragma unroll
        for (int s = 0; s < 16; ++s) ps[s] += __shfl_xor(ps[s], off, 64);
    int wave = tid >> 6;
    if ((tid & 63) == 0)
        #pragma unroll
        for (int s = 0; s < 16; ++s) sred[wave][s] = ps[s];
    __syncthreads();
    if (tid < 16) {
        sc0[n * 16 + tid] = sred[0][tid] + sred[1][tid] + sred[2][tid] + sred[3][tid];
        sc1[n * 16 + tid] = 0.f;
        sc2[n * 16 + tid] = 0.f;
    }
}

union LdsS {
    struct {
        half_t sA[32][BK + 8];
        half_t sB[4][16][BK + 8];
    } s;
    float pe[4][32][16];
};

__global__ __launch_bounds__(256) void k_step(const float* __restrict__ x,
        const half_t* __restrict__ h16c, half_t* __restrict__ h16n,
        const half_t* __restrict__ WhxT, const half_t* __restrict__ A16,
        const half_t* __restrict__ G16, const float* __restrict__ b,
        float* __restrict__ cbuf, const float* __restrict__ scC,
        float* __restrict__ scN, float* __restrict__ scZ,
        float* __restrict__ out, int t) {
    __shared__ LdsS L;
    __shared__ float wlds[32][16];
    int bid = blockIdx.x;
    int xcd = bid & 7, slot = bid >> 3;
    int mtile = slot & 7, jtile = slot >> 3;
    int n0 = mtile * 32;
    int j0 = xcd * 128 + jtile * 16;
    int tid = threadIdx.x, wv = tid >> 6, lane = tid & 63;

    if (bid < 16) scZ[bid * 256 + tid] = 0.f;
    if (tid < 32) {
        int n = n0 + tid;
        const float4* sp = (const float4*)(scC + n * 16);
        float4 u0 = sp[0], u1 = sp[1], u2 = sp[2], u3 = sp[3];
        float sc[16] = {u0.x, u0.y, u0.z, u0.w, u1.x, u1.y, u1.z, u1.w,
                        u2.x, u2.y, u2.z, u2.w, u3.x, u3.y, u3.z, u3.w};
        float m = -1e30f;
        #pragma unroll
        for (int s = 0; s < 16; ++s) { sc[s] *= 0.03125f; m = fmaxf(m, sc[s]); }
        float den = 0.f;
        #pragma unroll
        for (int s = 0; s < 16; ++s) { sc[s] = expf(sc[s] - m); den += sc[s]; }
        float inv = 1.f / den;
        #pragma unroll
        for (int s = 0; s < 16; ++s) wlds[tid][s] = sc[s] * inv;
    }

    f32x4 acc[2] = {};
    int srA = tid >> 3, scA = (tid & 7) * 16;
    int srB = tid >> 2, scB = (tid & 3) * 32;
    int gB = srB >> 4, jcB = srB & 15;

    for (int it = 0; it < KHX / BK; ++it) {
        int k0 = it * BK;
        {
            int n = n0 + srA;
            if (k0 < DD) {
                const float* src = x + ((size_t)n * TT + t) * DD + k0 + scA;
                float4 v0 = ((const float4*)src)[0];
                float4 v1 = ((const float4*)src)[1];
                float4 v2 = ((const float4*)src)[2];
                float4 v3 = ((const float4*)src)[3];
                half8 p0, p1;
                p0[0] = (half_t)v0.x; p0[1] = (half_t)v0.y; p0[2] = (half_t)v0.z; p0[3] = (half_t)v0.w;
                p0[4] = (half_t)v1.x; p0[5] = (half_t)v1.y; p0[6] = (half_t)v1.z; p0[7] = (half_t)v1.w;
                p1[0] = (half_t)v2.x; p1[1] = (half_t)v2.y; p1[2] = (half_t)v2.z; p1[3] = (half_t)v2.w;
                p1[4] = (half_t)v3.x; p1[5] = (half_t)v3.y; p1[6] = (half_t)v3.z; p1[7] = (half_t)v3.w;
                *(half8*)&L.s.sA[srA][scA]     = p0;
                *(half8*)&L.s.sA[srA][scA + 8] = p1;
            } else {
                const half_t* srch = h16c + (size_t)n * HH + (k0 - DD) + scA;
                uint4 u0 = ((const uint4*)srch)[0];
                uint4 u1 = ((const uint4*)srch)[1];
                *((uint4*)&L.s.sA[srA][scA])     = u0;
                *((uint4*)&L.s.sA[srA][scA + 8]) = u1;
            }
        }
        {
            const half_t* src = WhxT + ((size_t)(gB * HH + j0 + jcB)) * KHX + k0 + scB;
            uint4 u0 = ((const uint4*)src)[0];
            uint4 u1 = ((const uint4*)src)[1];
            uint4 u2 = ((const uint4*)src)[2];
            uint4 u3 = ((const uint4*)src)[3];
            *((uint4*)&L.s.sB[gB][jcB][scB])      = u0;
            *((uint4*)&L.s.sB[gB][jcB][scB + 8])  = u1;
            *((uint4*)&L.s.sB[gB][jcB][scB + 16]) = u2;
            *((uint4*)&L.s.sB[gB][jcB][scB + 24]) = u3;
        }
        __syncthreads();
        int row16 = lane & 15, kg = lane >> 4;
        #pragma unroll
        for (int kc = 0; kc < BK / 32; ++kc) {
            half8 bf = *(const half8*)&L.s.sB[wv][row16][kc * 32 + kg * 8];
            #pragma unroll
            for (int m = 0; m < 2; ++m) {
                half8 af = *(const half8*)&L.s.sA[row16 + m * 16][kc * 32 + kg * 8];
                acc[m] = __builtin_amdgcn_mfma_f32_16x16x32_f16(af, bf, acc[m], 0, 0, 0);
            }
        }
        __syncthreads();
    }
    {
        int col = lane & 15, rbase = (lane >> 4) * 4;
        #pragma unroll
        for (int m = 0; m < 2; ++m)
            #pragma unroll
            for (int q = 0; q < 4; ++q)
                L.pe[wv][m * 16 + rbase + q][col] = acc[m][q];
    }
    __syncthreads();
    #pragma unroll
    for (int q2 = 0; q2 < 2; ++q2) {
        int idx = tid + q2 * 256;
        int r = idx >> 4, jc = idx & 15;
        int n = n0 + r, j = j0 + jc;
        float wv16[16];
        #pragma unroll
        for (int s = 0; s < 16; ++s) wv16[s] = wlds[r][s];
        float v[4];
        v[0] = L.pe[0][r][jc] + b[j];
        v[1] = L.pe[1][r][jc] + b[HH + j];
        v[2] = L.pe[2][r][jc] + b[2 * HH + j];
        v[3] = L.pe[3][r][jc] + b[3 * HH + j];
        #pragma unroll
        for (int g = 0; g < 4; ++g) {
            const half8* gq = (const half8*)(G16 + ((size_t)n * 4096 + g * HH + j) * 16);
            half8 ga = gq[0], gb2 = gq[1];
            float a0 = 0.f;
            #pragma unroll
            for (int s = 0; s < 8; ++s)
                a0 += wv16[s] * (float)ga[s] + wv16[s + 8] * (float)gb2[s];
            v[g] += a0;
        }
        float ig = 1.f / (1.f + expf(-v[0]));
        float fg = 1.f / (1.f + expf(-v[1]));
        float og = 1.f / (1.f + expf(-v[2]));
        float gg = tanhf(v[3]);
        size_t ci = (size_t)n * HH + j;
        float cp = cbuf[ci];
        float cn = fg * cp + ig * gg;
        cbuf[ci] = cn;
        float hv = og * tanhf(cn);
        out[((size_t)n * TT + t) * HH + j] = hv;
        h16n[ci] = (half_t)hv;
        const half8* ap = (const half8*)(A16 + ci * 16);
        half8 a0 = ap[0], a1 = ap[1];
        float p[16];
        #pragma unroll
        for (int s = 0; s < 8; ++s) { p[s] = hv * (float)a0[s]; p[s + 8] = hv * (float)a1[s]; }
        #pragma unroll
        for (int msk = 1; msk < 16; msk <<= 1)
            #pragma unroll
            for (int s = 0; s < 16; ++s) p[s] += __shfl_xor(p[s], msk, 64);
        float myp = 0.f;
        #pragma unroll
        for (int s = 0; s < 16; ++s) myp = (jc == s) ? p[s] : myp;
        atomicAdd(scN + n * 16 + jc, myp);
    }
}

// ========================= FALLBACK (round-1, proven) =========================

__global__ __launch_bounds__(256) void fb_wconv(const float* __restrict__ Wx,
        const float* __restrict__ Wh, const float* __restrict__ Wa,
        half_t* __restrict__ WT) {
    __shared__ half_t tile[64][65];
    int bk = blockIdx.x % 40;
    int bn = blockIdx.x / 40;
    int k0 = bk * 64, n0 = bn * 64;
    #pragma unroll
    for (int i = 0; i < 16; ++i) {
        int idx = i * 256 + threadIdx.x;
        int r = idx >> 6, c = idx & 63;
        int k = k0 + r, n = n0 + c;
        float v;
        if (k < DD)            v = Wx[(size_t)k * 4096 + n];
        else if (k < DD + HH)  v = Wh[(size_t)(k - DD) * 4096 + n];
        else                   v = Wa[(size_t)(k - DD - HH) * 4096 + n];
        tile[c][r] = (half_t)v;
    }
    __syncthreads();
    #pragma unroll
    for (int i = 0; i < 16; ++i) {
        int idx = i * 256 + threadIdx.x;
        int r = idx >> 6, c = idx & 63;
        WT[(size_t)(n0 + r) * KFB + k0 + c] = tile[r][c];
    }
}

__global__ __launch_bounds__(256) void fb_init(const float* __restrict__ A,
        float* __restrict__ h0, float* __restrict__ c0) {
    int n = blockIdx.x;
    #pragma unroll
    for (int r = 0; r < 4; ++r) {
        int h = threadIdx.x + r * 256;
        const float4* ap = (const float4*)(A + ((size_t)n * HH + h) * 16);
        float s = 0.f;
        #pragma unroll
        for (int q = 0; q < 4; ++q) {
            float4 v = ap[q];
            s += v.x + v.y + v.z + v.w;
        }
        s *= (1.f / 16.f);
        h0[n * HH + h] = s;
        c0[n * HH + h] = s;
    }
}

__global__ __launch_bounds__(256) void fb_attn(const float* __restrict__ A,
        const float* __restrict__ hprev, long long hstride,
        half_t* __restrict__ h16, half_t* __restrict__ attn16) {
    __shared__ float sh[HH];
    __shared__ float sred[4][16];
    int n = blockIdx.x;
    const float* hp = hprev + (size_t)n * hstride;
    #pragma unroll
    for (int r = 0; r < 4; ++r) {
        int h = threadIdx.x + r * 256;
        float v = hp[h];
        sh[h] = v;
        h16[n * HH + h] = (half_t)v;
    }
    __syncthreads();
    float a[4][16];
    float ps[16];
    #pragma unroll
    for (int s = 0; s < 16; ++s) ps[s] = 0.f;
    #pragma unroll
    for (int r = 0; r < 4; ++r) {
        int h = threadIdx.x + r * 256;
        const float4* ap = (const float4*)(A + ((size_t)n * HH + h) * 16);
        float4 v0 = ap[0], v1 = ap[1], v2 = ap[2], v3 = ap[3];
        a[r][0] = v0.x;  a[r][1] = v0.y;  a[r][2]  = v0.z;  a[r][3]  = v0.w;
        a[r][4] = v1.x;  a[r][5] = v1.y;  a[r][6]  = v1.z;  a[r][7]  = v1.w;
        a[r][8] = v2.x;  a[r][9] = v2.y;  a[r][10] = v2.z;  a[r][11] = v2.w;
        a[r][12] = v3.x; a[r][13] = v3.y; a[r][14] = v3.z;  a[r][15] = v3.w;
        float hh = sh[h];
        #pragma unroll
        for (int s = 0; s < 16; ++s) ps[s] += hh * a[r][s];
    }
    #pragma unroll
    for (int off = 32; off; off >>= 1)
        #pragma unroll
        for (int s = 0; s < 16; ++s) ps[s] += __shfl_xor(ps[s], off, 64);
    int wave = threadIdx.x >> 6;
    if ((threadIdx.x & 63) == 0)
        #pragma unroll
        for (int s = 0; s < 16; ++s) sred[wave][s] = ps[s];
    __syncthreads();
    float sc[16], m = -1e30f;
    #pragma unroll
    for (int s = 0; s < 16; ++s) {
        sc[s] = (sred[0][s] + sred[1][s] + sred[2][s] + sred[3][s]) * 0.03125f;
        m = fmaxf(m, sc[s]);
    }
    float den = 0.f;
    #pragma unroll
    for (int s = 0; s < 16; ++s) { sc[s] = expf(sc[s] - m); den += sc[s]; }
    float inv = 1.f / den;
    #pragma unroll
    for (int r = 0; r < 4; ++r) {
        int h = threadIdx.x + r * 256;
        float acc = 0.f;
        #pragma unroll
        for (int s = 0; s < 16; ++s) acc += a[r][s] * sc[s];
        attn16[n * HH + h] = (half_t)(acc * inv);
    }
}

union LdsFB {
    struct {
        half_t sA[32][BK + 8];
        half_t sB[4][16][BK + 8];
    } s;
    float pe[4][32][16];
};

__global__ __launch_bounds__(256) void fb_gemm(const float* __restrict__ x,
        const half_t* __restrict__ h16, const half_t* __restrict__ attn16,
        const half_t* __restrict__ WT, const float* __restrict__ b,
        float* __restrict__ cbuf, float* __restrict__ out, int t) {
    __shared__ LdsFB L;
    int bid = blockIdx.x;
    int xcd = bid & 7;
    int slot = bid >> 3;
    int mtile = slot & 7;
    int jtile = slot >> 3;
    int m0 = mtile * 32;
    int j0 = xcd * 128 + jtile * 16;
    int tid = threadIdx.x;
    int wv = tid >> 6, lane = tid & 63;
    f32x4 acc[2] = {};
    int srA = tid >> 3, scA = (tid & 7) * 16;
    int srB = tid >> 2, scB = (tid & 3) * 32;
    int gB = srB >> 4, jcB = srB & 15;
    for (int it = 0; it < KFB / BK; ++it) {
        int k0 = it * BK;
        {
            int n = m0 + srA;
            if (k0 < DD) {
                const float* src = x + ((size_t)n * TT + t) * DD + k0 + scA;
                float4 v0 = ((const float4*)src)[0];
                float4 v1 = ((const float4*)src)[1];
                float4 v2 = ((const float4*)src)[2];
                float4 v3 = ((const float4*)src)[3];
                half8 p0, p1;
                p0[0] = (half_t)v0.x; p0[1] = (half_t)v0.y; p0[2] = (half_t)v0.z; p0[3] = (half_t)v0.w;
                p0[4] = (half_t)v1.x; p0[5] = (half_t)v1.y; p0[6] = (half_t)v1.z; p0[7] = (half_t)v1.w;
                p1[0] = (half_t)v2.x; p1[1] = (half_t)v2.y; p1[2] = (half_t)v2.z; p1[3] = (half_t)v2.w;
                p1[4] = (half_t)v3.x; p1[5] = (half_t)v3.y; p1[6] = (half_t)v3.z; p1[7] = (half_t)v3.w;
                *(half8*)&L.s.sA[srA][scA]     = p0;
                *(half8*)&L.s.sA[srA][scA + 8] = p1;
            } else {
                const half_t* srch = (k0 < DD + HH)
                    ? (h16    + (size_t)n * HH + (k0 - DD)      + scA)
                    : (attn16 + (size_t)n * HH + (k0 - DD - HH) + scA);
                uint4 u0 = ((const uint4*)srch)[0];
                uint4 u1 = ((const uint4*)srch)[1];
                *((uint4*)&L.s.sA[srA][scA])     = u0;
                *((uint4*)&L.s.sA[srA][scA + 8]) = u1;
            }
        }
        {
            const half_t* src = WT + ((size_t)(gB * HH + j0 + jcB)) * KFB + k0 + scB;
            uint4 u0 = ((const uint4*)src)[0];
            uint4 u1 = ((const uint4*)src)[1];
            uint4 u2 = ((const uint4*)src)[2];
            uint4 u3 = ((const uint4*)src)[3];
            *((uint4*)&L.s.sB[gB][jcB][scB])      = u0;
            *((uint4*)&L.s.sB[gB][jcB][scB + 8])  = u1;
            *((uint4*)&L.s.sB[gB][jcB][scB + 16]) = u2;
            *((uint4*)&L.s.sB[gB][jcB][scB + 24]) = u3;
        }
        __syncthreads();
        int row16 = lane & 15, kg = lane >> 4;
        #pragma unroll
        for (int kc = 0; kc < BK / 32; ++kc) {
            half8 bf = *(const half8*)&L.s.sB[wv][row16][kc * 32 + kg * 8];
            #pragma unroll
            for (int m = 0; m < 2; ++m) {
                half8 af = *(const half8*)&L.s.sA[row16 + m * 16][kc * 32 + kg * 8];
                acc[m] = __builtin_amdgcn_mfma_f32_16x16x32_f16(af, bf, acc[m], 0, 0, 0);
            }
        }
        __syncthreads();
    }
    {
        int col = lane & 15, rbase = (lane >> 4) * 4;
        #pragma unroll
        for (int m = 0; m < 2; ++m)
            #pragma unroll
            for (int q = 0; q < 4; ++q)
                L.pe[wv][m * 16 + rbase + q][col] = acc[m][q];
    }
    __syncthreads();
    #pragma unroll
    for (int q2 = 0; q2 < 2; ++q2) {
        int idx = tid + q2 * 256;
        int r = idx >> 4, jc = idx & 15;
        int n = m0 + r, j = j0 + jc;
        float vi = L.pe[0][r][jc] + b[j];
        float vf = L.pe[1][r][jc] + b[HH + j];
        float vo = L.pe[2][r][jc] + b[2 * HH + j];
        float vg = L.pe[3][r][jc] + b[3 * HH + j];
        float ig = 1.f / (1.f + expf(-vi));
        float fg = 1.f / (1.f + expf(-vf));
        float og = 1.f / (1.f + expf(-vo));
        float gg = tanhf(vg);
        size_t ci = (size_t)n * HH + j;
        float cp = cbuf[ci];
        float cn = fg * cp + ig * gg;
        cbuf[ci] = cn;
        out[((size_t)n * TT + t) * HH + j] = og * tanhf(cn);
    }
}

// ========================= HOST =========================

extern "C" void kernel_launch(void* const* d_in, const int* in_sizes, int n_in,
                              void* d_out, int out_size, void* d_ws, size_t ws_size,
                              hipStream_t stream) {
    const float* x  = (const float*)d_in[0];
    const float* A  = (const float*)d_in[1];
    const float* Wx = (const float*)d_in[2];
    const float* Wh = (const float*)d_in[3];
    const float* Wa = (const float*)d_in[4];
    const float* b  = (const float*)d_in[5];
    float* out = (float*)d_out;
    char* ws = (char*)d_ws;

    int maxb = 0;
    hipError_t oe = hipOccupancyMaxActiveBlocksPerMultiprocessor(&maxb, k_steps4, 512, 0);
    bool persistent_ok = (oe == hipSuccess && maxb >= 1);

    if (ws_size >= 375439616ULL && persistent_ok) {
        // fast path: XW-precompute + W-resident 8-wave persistent, sliced scores
        half_t* WhxT = (half_t*)(ws);                       // 12,582,912
        half_t* WaT  = (half_t*)(ws + 12582912);            //  8,388,608
        half_t* A16  = (half_t*)(ws + 20971520);            //  8,388,608
        half_t* AsT  = (half_t*)(ws + 29360128);            //  8,388,608 (freed after k_gemm_G)
        half_t* G16  = (half_t*)(ws + 37748736);            // 33,554,432
        half_t* h16a = (half_t*)(ws + 71303168);            //    524,288
        half_t* h16b = (half_t*)(ws + 71827456);            //    524,288
        float*  cb   = (float*) (ws + 72351744);            //  1,048,576
        half_t* x16  = (half_t*)(ws + 73449472);            // 33,554,432
        int*    bar  = (int*)   (ws + 107003904);           // 256 B
        half_t* XW16 = (half_t*)(ws + 107004160);           // 268,435,456
        // 8-slice score triple buffers live in the freed AsT region (after k_gemm_G)
        float*  sc0  = (float*)(ws + 29360128);             // 32,768 each
        float*  sc1  = (float*)(ws + 29360128 + 32768);
        float*  sc2  = (float*)(ws + 29360128 + 65536);

        hipLaunchKernelGGL(k_trans, dim3(8 * 64),  dim3(256), 0, stream, Wx, WhxT, KHX, 0,   8);
        hipLaunchKernelGGL(k_trans, dim3(16 * 64), dim3(256), 0, stream, Wh, WhxT, KHX, 512, 16);
        hipLaunchKernelGGL(k_trans, dim3(16 * 64), dim3(256), 0, stream, Wa, WaT,  HH,  0,   16);
        hipLaunchKernelGGL(k_convX, dim3(2048), dim3(256), 0, stream, x, x16);
        hipLaunchKernelGGL(k_convA2, dim3(256), dim3(256), 0, stream, A, A16, AsT, cb, h16a);
        hipLaunchKernelGGL(k_gemm_G, dim3(NB * 64), dim3(256), 0, stream, AsT, WaT, G16);
        hipLaunchKernelGGL(k_gemm_XW, dim3(256 * 64), dim3(256), 0, stream, x16, WhxT, XW16);
        hipLaunchKernelGGL(k_initsc, dim3(256), dim3(256), 0, stream, h16a, A16, sc0, sc1, sc2);
        hipMemsetAsync(bar, 0, 256, stream);
        hipLaunchKernelGGL(k_steps4, dim3(NBLK4), dim3(512), 0, stream,
                           XW16, h16a, h16b, WhxT, A16, G16, b, cb,
                           sc0, sc1, sc2, out, bar);
    } else if (ws_size >= 73449472ULL) {
        // round-2 mid path (proven)
        half_t* WhxT = (half_t*)(ws);
        half_t* WaT  = (half_t*)(ws + 12582912);
        half_t* A16  = (half_t*)(ws + 20971520);
        half_t* AsT  = (half_t*)(ws + 29360128);
        half_t* G16  = (half_t*)(ws + 37748736);
        half_t* h16a = (half_t*)(ws + 71303168);
        half_t* h16b = (half_t*)(ws + 71827456);
        float*  cb   = (float*) (ws + 72351744);
        float*  sc0  = (float*) (ws + 73400320);
        float*  sc1  = (float*) (ws + 73416704);
        float*  sc2  = (float*) (ws + 73433088);
        float* scb[3] = {sc0, sc1, sc2};

        hipLaunchKernelGGL(k_trans, dim3(8 * 64),  dim3(256), 0, stream, Wx, WhxT, KHX, 0,   8);
        hipLaunchKernelGGL(k_trans, dim3(16 * 64), dim3(256), 0, stream, Wh, WhxT, KHX, 512, 16);
        hipLaunchKernelGGL(k_trans, dim3(16 * 64), dim3(256), 0, stream, Wa, WaT,  HH,  0,   16);
        hipLaunchKernelGGL(k_convA, dim3(256), dim3(256), 0, stream,
                           A, A16, AsT, cb, h16a, sc0, sc1, sc2);
        hipLaunchKernelGGL(k_gemm_G, dim3(NB * 64), dim3(256), 0, stream, AsT, WaT, G16);
        for (int t = 0; t < TT; ++t) {
            float* scC = scb[t % 3];
            float* scN = scb[(t + 1) % 3];
            float* scZ = scb[(t + 2) % 3];
            half_t* h16c = (t & 1) ? h16b : h16a;
            half_t* h16n = (t & 1) ? h16a : h16b;
            hipLaunchKernelGGL(k_step, dim3(512), dim3(256), 0, stream,
                               x, h16c, h16n, WhxT, A16, G16, b, cb, scC, scN, scZ, out, t);
        }
    } else {
        // round-1 fallback (24.1 MB)
        half_t* WT  = (half_t*)ws;
        float*  h0  = (float*)(ws + 20971520);
        float*  cb  = (float*)(ws + 22020096);
        half_t* h16 = (half_t*)(ws + 23068672);
        half_t* a16 = (half_t*)(ws + 23592960);
        hipLaunchKernelGGL(fb_wconv, dim3(2560), dim3(256), 0, stream, Wx, Wh, Wa, WT);
        hipLaunchKernelGGL(fb_init, dim3(256), dim3(256), 0, stream, A, h0, cb);
        for (int t = 0; t < TT; ++t) {
            const float* hp = (t == 0) ? h0 : (out + (size_t)(t - 1) * HH);
            long long hstride = (t == 0) ? (long long)HH : (long long)TT * HH;
            hipLaunchKernelGGL(fb_attn, dim3(256), dim3(256), 0, stream, A, hp, hstride, h16, a16);
            hipLaunchKernelGGL(fb_gemm, dim3(512), dim3(256), 0, stream,
                               x, h16, a16, WT, b, cb, out, t);
        }
    }
}

// Round 7
// 4625.831 us; speedup vs baseline: 1.0034x; 1.0034x over previous
//
#include <hip/hip_runtime.h>
#include <math.h>

#define NB 256
#define TT 128
#define DD 512
#define HH 1024
#define KHX 1536    // 512 (x) + 1024 (h)
#define KFB 2560
#define BK 128
#define NBLK5 256
#define NHALF 128   // blocks per sync domain (one n-half)

typedef _Float16 half_t;
typedef _Float16 half8 __attribute__((ext_vector_type(8)));
typedef _Float16 half4v __attribute__((ext_vector_type(4)));
typedef _Float16 half2v __attribute__((ext_vector_type(2)));
typedef float f32x4 __attribute__((ext_vector_type(4)));

// ========================= PRE-KERNELS =========================

__global__ __launch_bounds__(256) void k_trans(const float* __restrict__ src,
        half_t* __restrict__ dst, int kstride, int koff, int nkt) {
    __shared__ half_t tile[64][65];
    int bk = blockIdx.x % nkt;
    int bn = blockIdx.x / nkt;
    int k0 = bk * 64, n0 = bn * 64;
    #pragma unroll
    for (int i = 0; i < 16; ++i) {
        int idx = i * 256 + threadIdx.x;
        int r = idx >> 6, c = idx & 63;
        tile[c][r] = (half_t)src[(size_t)(k0 + r) * 4096 + n0 + c];
    }
    __syncthreads();
    #pragma unroll
    for (int i = 0; i < 16; ++i) {
        int idx = i * 256 + threadIdx.x;
        int r = idx >> 6, c = idx & 63;
        dst[(size_t)(n0 + r) * kstride + koff + k0 + c] = tile[r][c];
    }
}

__global__ __launch_bounds__(256) void k_convX(const float* __restrict__ x,
        half_t* __restrict__ x16) {
    size_t base = ((size_t)blockIdx.x * 256 + threadIdx.x) * 32;
    #pragma unroll
    for (int u = 0; u < 4; ++u) {
        float4 a = ((const float4*)(x + base))[2 * u];
        float4 c = ((const float4*)(x + base))[2 * u + 1];
        half8 p;
        p[0] = (half_t)a.x; p[1] = (half_t)a.y; p[2] = (half_t)a.z; p[3] = (half_t)a.w;
        p[4] = (half_t)c.x; p[5] = (half_t)c.y; p[6] = (half_t)c.z; p[7] = (half_t)c.w;
        ((half8*)(x16 + base))[u] = p;
    }
}

__global__ __launch_bounds__(256) void k_convA2(const float* __restrict__ A,
        half_t* __restrict__ A16, half_t* __restrict__ AsT,
        float* __restrict__ cbuf, half_t* __restrict__ h16) {
    int n = blockIdx.x, tid = threadIdx.x;
    #pragma unroll
    for (int r = 0; r < 4; ++r) {
        int h = tid + r * 256;
        const float4* ap = (const float4*)(A + ((size_t)n * HH + h) * 16);
        float4 v0 = ap[0], v1 = ap[1], v2 = ap[2], v3 = ap[3];
        float a[16];
        a[0]=v0.x; a[1]=v0.y; a[2] =v0.z; a[3] =v0.w;
        a[4]=v1.x; a[5]=v1.y; a[6] =v1.z; a[7] =v1.w;
        a[8]=v2.x; a[9]=v2.y; a[10]=v2.z; a[11]=v2.w;
        a[12]=v3.x; a[13]=v3.y; a[14]=v3.z; a[15]=v3.w;
        float hv = 0.f;
        #pragma unroll
        for (int s = 0; s < 16; ++s) hv += a[s];
        hv *= (1.f / 16.f);
        size_t ci = (size_t)n * HH + h;
        cbuf[ci] = hv;
        h16[ci] = (half_t)hv;
        half8 q0, q1;
        #pragma unroll
        for (int s = 0; s < 8; ++s) { q0[s] = (half_t)a[s]; q1[s] = (half_t)a[s + 8]; }
        *(half8*)(A16 + ci * 16) = q0;
        *(half8*)(A16 + ci * 16 + 8) = q1;
        #pragma unroll
        for (int s = 0; s < 16; ++s)
            AsT[(size_t)n * 16 * HH + (size_t)s * HH + h] = (half_t)a[s];
    }
}

__global__ __launch_bounds__(256) void k_initsc(const half_t* __restrict__ h16,
        const half_t* __restrict__ A16,
        float* __restrict__ sc0, float* __restrict__ sc1, float* __restrict__ sc2) {
    __shared__ float sred[4][16];
    int n = blockIdx.x, tid = threadIdx.x;
    float ps[16];
    #pragma unroll
    for (int s = 0; s < 16; ++s) ps[s] = 0.f;
    #pragma unroll
    for (int r = 0; r < 4; ++r) {
        int h = tid + r * 256;
        size_t ci = (size_t)n * HH + h;
        float hv = (float)h16[ci];
        const half8* ap = (const half8*)(A16 + ci * 16);
        half8 a0 = ap[0], a1 = ap[1];
        #pragma unroll
        for (int s = 0; s < 8; ++s) {
            ps[s]     += hv * (float)a0[s];
            ps[s + 8] += hv * (float)a1[s];
        }
    }
    #pragma unroll
    for (int off = 32; off; off >>= 1)
        #pragma unroll
        for (int s = 0; s < 16; ++s) ps[s] += __shfl_xor(ps[s], off, 64);
    int wave = tid >> 6;
    if ((tid & 63) == 0)
        #pragma unroll
        for (int s = 0; s < 16; ++s) sred[wave][s] = ps[s];
    __syncthreads();
    if (tid < 16)
        sc0[(size_t)n * 16 + tid] =
            sred[0][tid] + sred[1][tid] + sred[2][tid] + sred[3][tid];
    if (tid < 112) {
        int x = 1 + tid / 16, s = tid % 16;
        sc0[((size_t)x * 256 + n) * 16 + s] = 0.f;
    }
    if (tid < 128) {
        int x = tid / 16, s = tid % 16;
        sc1[((size_t)x * 256 + n) * 16 + s] = 0.f;
        sc2[((size_t)x * 256 + n) * 16 + s] = 0.f;
    }
}

__global__ __launch_bounds__(256) void k_gemm_G(const half_t* __restrict__ AsT,
        const half_t* __restrict__ WaT, half_t* __restrict__ G16) {
    __shared__ half_t sAs[16][BK + 8];
    __shared__ half_t sB[4][16][BK + 8];
    int bid = blockIdx.x;
    int n = bid >> 6, jt = bid & 63;
    int j0 = jt * 16;
    int tid = threadIdx.x, wv = tid >> 6, lane = tid & 63;
    f32x4 acc = {};
    int srB = tid >> 2, scB = (tid & 3) * 32;
    int gB = srB >> 4, jcB = srB & 15;
    for (int it = 0; it < HH / BK; ++it) {
        int k0 = it * BK;
        if (tid < 128) {
            int r = tid >> 3, c = (tid & 7) * 16;
            const uint4* sp = (const uint4*)(AsT + (size_t)n * 16 * HH + (size_t)r * HH + k0 + c);
            uint4 u0 = sp[0], u1 = sp[1];
            *(uint4*)&sAs[r][c] = u0;
            *(uint4*)&sAs[r][c + 8] = u1;
        }
        {
            const half_t* src = WaT + ((size_t)(gB * HH + j0 + jcB)) * HH + k0 + scB;
            uint4 u0 = ((const uint4*)src)[0];
            uint4 u1 = ((const uint4*)src)[1];
            uint4 u2 = ((const uint4*)src)[2];
            uint4 u3 = ((const uint4*)src)[3];
            *((uint4*)&sB[gB][jcB][scB])      = u0;
            *((uint4*)&sB[gB][jcB][scB + 8])  = u1;
            *((uint4*)&sB[gB][jcB][scB + 16]) = u2;
            *((uint4*)&sB[gB][jcB][scB + 24]) = u3;
        }
        __syncthreads();
        int row16 = lane & 15, kg = lane >> 4;
        #pragma unroll
        for (int kc = 0; kc < BK / 32; ++kc) {
            half8 bf = *(const half8*)&sB[wv][row16][kc * 32 + kg * 8];
            half8 af = *(const half8*)&sAs[row16][kc * 32 + kg * 8];
            acc = __builtin_amdgcn_mfma_f32_16x16x32_f16(af, bf, acc, 0, 0, 0);
        }
        __syncthreads();
    }
    int col = lane & 15, rbase = (lane >> 4) * 4;
    size_t jf = (size_t)wv * HH + j0 + col;
    half4v o;
    o[0] = (half_t)acc[0]; o[1] = (half_t)acc[1];
    o[2] = (half_t)acc[2]; o[3] = (half_t)acc[3];
    *(half4v*)(G16 + ((size_t)n * 4096 + jf) * 16 + rbase) = o;
}

__global__ __launch_bounds__(256) void k_gemm_XW(const half_t* __restrict__ x16,
        const half_t* __restrict__ WhxT, half_t* __restrict__ XW16) {
    __shared__ half_t sA[128][72];
    __shared__ half_t sB[64][72];
    int bid = blockIdx.x;
    int bm = bid & 255;
    int bj = bid >> 8;
    int row0 = bm * 128;
    int col0 = bj * 64;
    int tid = threadIdx.x, wv = tid >> 6, lane = tid & 63;
    int la = lane & 15, kg = lane >> 4;
    int mh = wv & 1, jh = wv >> 1;
    f32x4 acc[4][2] = {};
    int srA = tid >> 1, scA = (tid & 1) * 32;
    int srB = tid >> 2, scB = (tid & 3) * 16;
    for (int c = 0; c < 8; ++c) {
        {
            const uint4* sp = (const uint4*)(x16 + (size_t)(row0 + srA) * DD + c * 64 + scA);
            uint4 u0 = sp[0], u1 = sp[1];
            *(uint4*)&sA[srA][scA] = u0;
            *(uint4*)&sA[srA][scA + 8] = u1;
        }
        {
            const uint4* sp = (const uint4*)(WhxT + (size_t)(col0 + srB) * KHX + c * 64 + scB);
            *(uint4*)&sB[srB][scB] = sp[0];
        }
        __syncthreads();
        #pragma unroll
        for (int ks = 0; ks < 2; ++ks) {
            half8 b0 = *(const half8*)&sB[jh * 32 + la][ks * 32 + kg * 8];
            half8 b1 = *(const half8*)&sB[jh * 32 + 16 + la][ks * 32 + kg * 8];
            #pragma unroll
            for (int m = 0; m < 4; ++m) {
                half8 af = *(const half8*)&sA[mh * 64 + m * 16 + la][ks * 32 + kg * 8];
                acc[m][0] = __builtin_amdgcn_mfma_f32_16x16x32_f16(af, b0, acc[m][0], 0, 0, 0);
                acc[m][1] = __builtin_amdgcn_mfma_f32_16x16x32_f16(af, b1, acc[m][1], 0, 0, 0);
            }
        }
        __syncthreads();
    }
    __syncthreads();
    half_t (*Cl)[72] = sA;
    #pragma unroll
    for (int m = 0; m < 4; ++m)
        #pragma unroll
        for (int jt = 0; jt < 2; ++jt)
            #pragma unroll
            for (int q = 0; q < 4; ++q) {
                int rl = mh * 64 + m * 16 + kg * 4 + q;
                int cl = jh * 32 + jt * 16 + la;
                Cl[rl][cl] = (half_t)acc[m][jt][q];
            }
    __syncthreads();
    int g = col0 >> 10;
    #pragma unroll
    for (int i = 0; i < 4; ++i) {
        int idx = tid + i * 256;
        int rl = idx >> 3, grp = idx & 7;
        int R = row0 + rl;
        int t = R & 127, nn = R >> 7;
        int mh2 = nn >> 7, nl2 = nn & 127;
        int jb2 = ((col0 & 1023) >> 3) + grp;
        size_t dst = ((((size_t)t * 128 + jb2) * 2 + mh2) * 128 + nl2) * 32 + g * 8;
        *(half8*)(XW16 + dst) = *(const half8*)&Cl[rl][grp * 8];
    }
}

// ========================= PERSISTENT STEP KERNEL v5 =========================
// Direct-global A-fragments (no LDS staging, no GEMM barriers); per-half sync.

struct StepLds5 {
    half_t W[32][1028];               // 65,792 B, resident
    union {
        float sm[4][128][16];         // 32,768 B
        struct {
            float pe[128][33];        // 16,896 B
            float pad[384];           //  1,536 B
            float ps[2][128][18];     // 18,432 B
        } e;
    } u;
};

__device__ __forceinline__ void grid_sync5(int* cnt, int* flag, int inst) {
    __syncthreads();
    if (threadIdx.x == 0) {
        __threadfence();
        int prev = __hip_atomic_fetch_add(cnt, 1, __ATOMIC_RELAXED,
                                          __HIP_MEMORY_SCOPE_AGENT);
        if (prev == NHALF * (inst + 1) - 1) {
            __hip_atomic_store(flag, inst + 1, __ATOMIC_RELAXED,
                               __HIP_MEMORY_SCOPE_AGENT);
        } else {
            int guard = 0;
            while (__hip_atomic_load(flag, __ATOMIC_RELAXED,
                                     __HIP_MEMORY_SCOPE_AGENT) < inst + 1) {
                __builtin_amdgcn_s_sleep(2);
                if (++guard > (1 << 24)) break;
            }
        }
        __threadfence();
    }
    __syncthreads();
}

__global__ __launch_bounds__(512, 1) void k_steps5(
        const half_t* __restrict__ XW16, half_t* __restrict__ h16A,
        half_t* __restrict__ h16B, const half_t* __restrict__ WhxT,
        const half_t* __restrict__ A16, const half_t* __restrict__ G16,
        const float* __restrict__ b, const float* __restrict__ cbuf,
        float* __restrict__ sc0, float* __restrict__ sc1, float* __restrict__ sc2,
        float* __restrict__ out, int* __restrict__ bar) {
    __shared__ StepLds5 L;
    int bid = blockIdx.x;
    int mhalf = bid & 1, jb = bid >> 1;   // jb 0..127
    int n0 = mhalf * 128;
    int tid = threadIdx.x;
    int wv = tid >> 6, lane = tid & 63;
    int la = lane & 15, kg = lane >> 4;
    int slice = bid & 7;
    int* cnt  = bar + mhalf * 32;         // 128 B apart per half
    int* flag = bar + mhalf * 32 + 16;

    // ---- W_h (32 output-cols x 1024 k) into LDS once ----
    {
        int wr = tid >> 4, seg = tid & 15;
        const half_t* wsrc = WhxT + (size_t)((wr >> 3) * HH + jb * 8 + (wr & 7)) * KHX
                           + DD + seg * 64;
        #pragma unroll
        for (int i = 0; i < 8; ++i)
            *(uint4*)&L.W[wr][seg * 64 + i * 8] = ((const uint4*)wsrc)[i];
    }

    // ---- pinned invariants: thread owns (n, 2 j-cols) ----
    int n_l = tid & 127, jg2 = tid >> 7;
    int n = n0 + n_l;
    int jbase = jb * 8 + jg2 * 2;
    half8 gq[4][4];
    #pragma unroll
    for (int g = 0; g < 4; ++g) {
        const half8* gsrc = (const half8*)(G16 + ((size_t)n * 4096 + g * HH + jbase) * 16);
        #pragma unroll
        for (int i = 0; i < 4; ++i) gq[g][i] = gsrc[i];
    }
    half8 aq[4];
    {
        const half8* asrc = (const half8*)(A16 + ((size_t)n * HH + jbase) * 16);
        #pragma unroll
        for (int i = 0; i < 4; ++i) aq[i] = asrc[i];
    }
    float bb[4][2];
    #pragma unroll
    for (int g = 0; g < 4; ++g) {
        bb[g][0] = b[g * HH + jbase];
        bb[g][1] = b[g * HH + jbase + 1];
    }
    float creg[2];
    creg[0] = cbuf[(size_t)n * HH + jbase];
    creg[1] = cbuf[(size_t)n * HH + jbase + 1];

    float* scC = sc0; float* scN = sc1; float* scZ = sc2;
    half_t* h16c = h16A;
    half_t* h16n = h16B;

    half2v xwv[4];
    {
        const half_t* xwp = XW16 + (((size_t)jb * 2 + mhalf) * 128 + n_l) * 32;
        #pragma unroll
        for (int g = 0; g < 4; ++g) xwv[g] = *(const half2v*)(xwp + g * 8 + jg2 * 2);
    }

    for (int t = 0; t < TT; ++t) {
        // ---- mhalf-local zeroing of scZ (this half's n-range, all 8 slices) ----
        if (jb < 32) {
            int idx = jb * 512 + tid;          // 0..16383
            int sl = idx >> 11, rem = idx & 2047;
            int nn = rem >> 4, s = rem & 15;
            scZ[((size_t)sl * 256 + n0 + nn) * 16 + s] = 0.f;
        }

        // ---- softmax: thread sums 2 slices -> LDS, combine 4 ----
        {
            const float* p0 = scC + ((size_t)(jg2 * 2) * 256 + n) * 16;
            const float* p1 = scC + ((size_t)(jg2 * 2 + 1) * 256 + n) * 16;
            #pragma unroll
            for (int i = 0; i < 4; ++i) {
                float4 a = ((const float4*)p0)[i];
                float4 c = ((const float4*)p1)[i];
                float4 o;
                o.x = a.x + c.x; o.y = a.y + c.y; o.z = a.z + c.z; o.w = a.w + c.w;
                *(float4*)&L.u.sm[jg2][n_l][4 * i] = o;
            }
        }
        __syncthreads();
        float w16[16];
        {
            float sc[16];
            #pragma unroll
            for (int i = 0; i < 4; ++i) {
                float4 q0 = *(const float4*)&L.u.sm[0][n_l][4 * i];
                float4 q1 = *(const float4*)&L.u.sm[1][n_l][4 * i];
                float4 q2 = *(const float4*)&L.u.sm[2][n_l][4 * i];
                float4 q3 = *(const float4*)&L.u.sm[3][n_l][4 * i];
                sc[4 * i + 0] = q0.x + q1.x + q2.x + q3.x;
                sc[4 * i + 1] = q0.y + q1.y + q2.y + q3.y;
                sc[4 * i + 2] = q0.z + q1.z + q2.z + q3.z;
                sc[4 * i + 3] = q0.w + q1.w + q2.w + q3.w;
            }
            float m = -1e30f;
            #pragma unroll
            for (int s = 0; s < 16; ++s) { sc[s] *= 0.03125f; m = fmaxf(m, sc[s]); }
            float den = 0.f;
            #pragma unroll
            for (int s = 0; s < 16; ++s) { sc[s] = expf(sc[s] - m); den += sc[s]; }
            float inv = 1.f / den;
            #pragma unroll
            for (int s = 0; s < 16; ++s) w16[s] = sc[s] * inv;
        }
        __syncthreads();   // sm reads done before pe (aliased) is written

        // ---- GEMM: h @ Wh, A-fragments straight from global, NO barriers ----
        f32x4 acc0 = {}, acc1 = {};
        {
            const half_t* hrow = h16c + (size_t)(n0 + wv * 16 + la) * HH + kg * 8;
            #pragma unroll
            for (int c = 0; c < 32; ++c) {
                half8 af = *(const half8*)(hrow + c * 32);
                half8 b0 = *(const half8*)&L.W[la][c * 32 + kg * 8];
                half8 b1 = *(const half8*)&L.W[16 + la][c * 32 + kg * 8];
                acc0 = __builtin_amdgcn_mfma_f32_16x16x32_f16(af, b0, acc0, 0, 0, 0);
                acc1 = __builtin_amdgcn_mfma_f32_16x16x32_f16(af, b1, acc1, 0, 0, 0);
            }
        }

        // ---- C-frag exchange via pe ----
        #pragma unroll
        for (int q = 0; q < 4; ++q) {
            L.u.e.pe[wv * 16 + kg * 4 + q][la]      = acc0[q];
            L.u.e.pe[wv * 16 + kg * 4 + q][16 + la] = acc1[q];
        }
        __syncthreads();

        // ---- epilogue: gates + state + h + score partials ----
        float v[4][2];
        #pragma unroll
        for (int g = 0; g < 4; ++g) {
            #pragma unroll
            for (int jj = 0; jj < 2; ++jj) {
                float a0 = 0.f;
                #pragma unroll
                for (int s = 0; s < 16; ++s)
                    a0 += w16[s] * (float)gq[g][jj * 2 + (s >> 3)][s & 7];
                v[g][jj] = L.u.e.pe[n_l][g * 8 + jg2 * 2 + jj] + bb[g][jj]
                         + (float)xwv[g][jj] + a0;
            }
        }
        float hv[2];
        #pragma unroll
        for (int jj = 0; jj < 2; ++jj) {
            float ig = 1.f / (1.f + expf(-v[0][jj]));
            float fg = 1.f / (1.f + expf(-v[1][jj]));
            float og = 1.f / (1.f + expf(-v[2][jj]));
            float gg = tanhf(v[3][jj]);
            float cn = fg * creg[jj] + ig * gg;
            creg[jj] = cn;
            hv[jj] = og * tanhf(cn);
        }
        {
            float2 o2; o2.x = hv[0]; o2.y = hv[1];
            *(float2*)(out + ((size_t)n * TT + t) * HH + jbase) = o2;
            half2v h2; h2[0] = (half_t)hv[0]; h2[1] = (half_t)hv[1];
            *(half2v*)(h16n + (size_t)n * HH + jbase) = h2;
        }
        float p[16];
        #pragma unroll
        for (int s = 0; s < 16; ++s)
            p[s] = hv[0] * (float)aq[s >> 3][s & 7]
                 + hv[1] * (float)aq[2 + (s >> 3)][s & 7];
        int pair = jg2 >> 1;
        if ((jg2 & 1) == 0) {
            #pragma unroll
            for (int s = 0; s < 16; ++s) L.u.e.ps[pair][n_l][s] = p[s];
        }
        __syncthreads();
        if ((jg2 & 1) == 1) {
            #pragma unroll
            for (int s = 0; s < 16; ++s) L.u.e.ps[pair][n_l][s] += p[s];
        }
        __syncthreads();
        #pragma unroll
        for (int i = 0; i < 4; ++i) {
            int slot = tid * 4 + i;
            int nn = slot >> 4, s = slot & 15;
            atomicAdd(scN + ((size_t)slice * 256 + n0 + nn) * 16 + s,
                      L.u.e.ps[0][nn][s] + L.u.e.ps[1][nn][s]);
        }

        // ---- XW prefetch for t+1 hidden under the per-half grid sync ----
        if (t + 1 < TT) {
            half2v xwn[4];
            const half_t* xwp = XW16 + ((((size_t)(t + 1) * 128 + jb) * 2 + mhalf) * 128 + n_l) * 32;
            #pragma unroll
            for (int g = 0; g < 4; ++g) xwn[g] = *(const half2v*)(xwp + g * 8 + jg2 * 2);
            grid_sync5(cnt, flag, t);
            #pragma unroll
            for (int g = 0; g < 4; ++g) xwv[g] = xwn[g];
        }
        float* tmp = scC; scC = scN; scN = scZ; scZ = tmp;
        half_t* th = h16c; h16c = h16n; h16n = th;
    }
}

// ========================= MID PATH (round-2, proven) =========================

__global__ __launch_bounds__(256) void k_convA(const float* __restrict__ A,
        half_t* __restrict__ A16, half_t* __restrict__ AsT,
        float* __restrict__ cbuf, half_t* __restrict__ h16,
        float* __restrict__ sc0, float* __restrict__ sc1, float* __restrict__ sc2) {
    __shared__ float sred[4][16];
    int n = blockIdx.x, tid = threadIdx.x;
    float ps[16];
    #pragma unroll
    for (int s = 0; s < 16; ++s) ps[s] = 0.f;
    #pragma unroll
    for (int r = 0; r < 4; ++r) {
        int h = tid + r * 256;
        const float4* ap = (const float4*)(A + ((size_t)n * HH + h) * 16);
        float4 v0 = ap[0], v1 = ap[1], v2 = ap[2], v3 = ap[3];
        float a[16];
        a[0]=v0.x; a[1]=v0.y; a[2] =v0.z; a[3] =v0.w;
        a[4]=v1.x; a[5]=v1.y; a[6] =v1.z; a[7] =v1.w;
        a[8]=v2.x; a[9]=v2.y; a[10]=v2.z; a[11]=v2.w;
        a[12]=v3.x; a[13]=v3.y; a[14]=v3.z; a[15]=v3.w;
        float hv = 0.f;
        #pragma unroll
        for (int s = 0; s < 16; ++s) hv += a[s];
        hv *= (1.f / 16.f);
        size_t ci = (size_t)n * HH + h;
        cbuf[ci] = hv;
        h16[ci] = (half_t)hv;
        half8 q0, q1;
        #pragma unroll
        for (int s = 0; s < 8; ++s) { q0[s] = (half_t)a[s]; q1[s] = (half_t)a[s + 8]; }
        *(half8*)(A16 + ci * 16) = q0;
        *(half8*)(A16 + ci * 16 + 8) = q1;
        #pragma unroll
        for (int s = 0; s < 16; ++s)
            AsT[(size_t)n * 16 * HH + (size_t)s * HH + h] = (half_t)a[s];
        #pragma unroll
        for (int s = 0; s < 16; ++s) ps[s] += hv * a[s];
    }
    #pragma unroll
    for (int off = 32; off; off >>= 1)
        #pragma unroll
        for (int s = 0; s < 16; ++s) ps[s] += __shfl_xor(ps[s], off, 64);
    int wave = tid >> 6;
    if ((tid & 63) == 0)
        #pragma unroll
        for (int s = 0; s < 16; ++s) sred[wave][s] = ps[s];
    __syncthreads();
    if (tid < 16) {
        sc0[n * 16 + tid] = sred[0][tid] + sred[1][tid] + sred[2][tid] + sred[3][tid];
        sc1[n * 16 + tid] = 0.f;
        sc2[n * 16 + tid] = 0.f;
    }
}

union LdsS {
    struct {
        half_t sA[32][BK + 8];
        half_t sB[4][16][BK + 8];
    } s;
    float pe[4][32][16];
};

__global__ __launch_bounds__(256) void k_step(const float* __restrict__ x,
        const half_t* __restrict__ h16c, half_t* __restrict__ h16n,
        const half_t* __restrict__ WhxT, const half_t* __restrict__ A16,
        const half_t* __restrict__ G16, const float* __restrict__ b,
        float* __restrict__ cbuf, const float* __restrict__ scC,
        float* __restrict__ scN, float* __restrict__ scZ,
        float* __restrict__ out, int t) {
    __shared__ LdsS L;
    __shared__ float wlds[32][16];
    int bid = blockIdx.x;
    int xcd = bid & 7, slot = bid >> 3;
    int mtile = slot & 7, jtile = slot >> 3;
    int n0 = mtile * 32;
    int j0 = xcd * 128 + jtile * 16;
    int tid = threadIdx.x, wv = tid >> 6, lane = tid & 63;

    if (bid < 16) scZ[bid * 256 + tid] = 0.f;
    if (tid < 32) {
        int n = n0 + tid;
        const float4* sp = (const float4*)(scC + n * 16);
        float4 u0 = sp[0], u1 = sp[1], u2 = sp[2], u3 = sp[3];
        float sc[16] = {u0.x, u0.y, u0.z, u0.w, u1.x, u1.y, u1.z, u1.w,
                        u2.x, u2.y, u2.z, u2.w, u3.x, u3.y, u3.z, u3.w};
        float m = -1e30f;
        #pragma unroll
        for (int s = 0; s < 16; ++s) { sc[s] *= 0.03125f; m = fmaxf(m, sc[s]); }
        float den = 0.f;
        #pragma unroll
        for (int s = 0; s < 16; ++s) { sc[s] = expf(sc[s] - m); den += sc[s]; }
        float inv = 1.f / den;
        #pragma unroll
        for (int s = 0; s < 16; ++s) wlds[tid][s] = sc[s] * inv;
    }

    f32x4 acc[2] = {};
    int srA = tid >> 3, scA = (tid & 7) * 16;
    int srB = tid >> 2, scB = (tid & 3) * 32;
    int gB = srB >> 4, jcB = srB & 15;

    for (int it = 0; it < KHX / BK; ++it) {
        int k0 = it * BK;
        {
            int n = n0 + srA;
            if (k0 < DD) {
                const float* src = x + ((size_t)n * TT + t) * DD + k0 + scA;
                float4 v0 = ((const float4*)src)[0];
                float4 v1 = ((const float4*)src)[1];
                float4 v2 = ((const float4*)src)[2];
                float4 v3 = ((const float4*)src)[3];
                half8 p0, p1;
                p0[0] = (half_t)v0.x; p0[1] = (half_t)v0.y; p0[2] = (half_t)v0.z; p0[3] = (half_t)v0.w;
                p0[4] = (half_t)v1.x; p0[5] = (half_t)v1.y; p0[6] = (half_t)v1.z; p0[7] = (half_t)v1.w;
                p1[0] = (half_t)v2.x; p1[1] = (half_t)v2.y; p1[2] = (half_t)v2.z; p1[3] = (half_t)v2.w;
                p1[4] = (half_t)v3.x; p1[5] = (half_t)v3.y; p1[6] = (half_t)v3.z; p1[7] = (half_t)v3.w;
                *(half8*)&L.s.sA[srA][scA]     = p0;
                *(half8*)&L.s.sA[srA][scA + 8] = p1;
            } else {
                const half_t* srch = h16c + (size_t)n * HH + (k0 - DD) + scA;
                uint4 u0 = ((const uint4*)srch)[0];
                uint4 u1 = ((const uint4*)srch)[1];
                *((uint4*)&L.s.sA[srA][scA])     = u0;
                *((uint4*)&L.s.sA[srA][scA + 8]) = u1;
            }
        }
        {
            const half_t* src = WhxT + ((size_t)(gB * HH + j0 + jcB)) * KHX + k0 + scB;
            uint4 u0 = ((const uint4*)src)[0];
            uint4 u1 = ((const uint4*)src)[1];
            uint4 u2 = ((const uint4*)src)[2];
            uint4 u3 = ((const uint4*)src)[3];
            *((uint4*)&L.s.sB[gB][jcB][scB])      = u0;
            *((uint4*)&L.s.sB[gB][jcB][scB + 8])  = u1;
            *((uint4*)&L.s.sB[gB][jcB][scB + 16]) = u2;
            *((uint4*)&L.s.sB[gB][jcB][scB + 24]) = u3;
        }
        __syncthreads();
        int row16 = lane & 15, kg = lane >> 4;
        #pragma unroll
        for (int kc = 0; kc < BK / 32; ++kc) {
            half8 bf = *(const half8*)&L.s.sB[wv][row16][kc * 32 + kg * 8];
            #pragma unroll
            for (int m = 0; m < 2; ++m) {
                half8 af = *(const half8*)&L.s.sA[row16 + m * 16][kc * 32 + kg * 8];
                acc[m] = __builtin_amdgcn_mfma_f32_16x16x32_f16(af, bf, acc[m], 0, 0, 0);
            }
        }
        __syncthreads();
    }
    {
        int col = lane & 15, rbase = (lane >> 4) * 4;
        #pragma unroll
        for (int m = 0; m < 2; ++m)
            #pragma unroll
            for (int q = 0; q < 4; ++q)
                L.pe[wv][m * 16 + rbase + q][col] = acc[m][q];
    }
    __syncthreads();
    #pragma unroll
    for (int q2 = 0; q2 < 2; ++q2) {
        int idx = tid + q2 * 256;
        int r = idx >> 4, jc = idx & 15;
        int n = n0 + r, j = j0 + jc;
        float wv16[16];
        #pragma unroll
        for (int s = 0; s < 16; ++s) wv16[s] = wlds[r][s];
        float v[4];
        v[0] = L.pe[0][r][jc] + b[j];
        v[1] = L.pe[1][r][jc] + b[HH + j];
        v[2] = L.pe[2][r][jc] + b[2 * HH + j];
        v[3] = L.pe[3][r][jc] + b[3 * HH + j];
        #pragma unroll
        for (int g = 0; g < 4; ++g) {
            const half8* gq = (const half8*)(G16 + ((size_t)n * 4096 + g * HH + j) * 16);
            half8 ga = gq[0], gb2 = gq[1];
            float a0 = 0.f;
            #pragma unroll
            for (int s = 0; s < 8; ++s)
                a0 += wv16[s] * (float)ga[s] + wv16[s + 8] * (float)gb2[s];
            v[g] += a0;
        }
        float ig = 1.f / (1.f + expf(-v[0]));
        float fg = 1.f / (1.f + expf(-v[1]));
        float og = 1.f / (1.f + expf(-v[2]));
        float gg = tanhf(v[3]);
        size_t ci = (size_t)n * HH + j;
        float cp = cbuf[ci];
        float cn = fg * cp + ig * gg;
        cbuf[ci] = cn;
        float hv = og * tanhf(cn);
        out[((size_t)n * TT + t) * HH + j] = hv;
        h16n[ci] = (half_t)hv;
        const half8* ap = (const half8*)(A16 + ci * 16);
        half8 a0 = ap[0], a1 = ap[1];
        float p[16];
        #pragma unroll
        for (int s = 0; s < 8; ++s) { p[s] = hv * (float)a0[s]; p[s + 8] = hv * (float)a1[s]; }
        #pragma unroll
        for (int msk = 1; msk < 16; msk <<= 1)
            #pragma unroll
            for (int s = 0; s < 16; ++s) p[s] += __shfl_xor(p[s], msk, 64);
        float myp = 0.f;
        #pragma unroll
        for (int s = 0; s < 16; ++s) myp = (jc == s) ? p[s] : myp;
        atomicAdd(scN + n * 16 + jc, myp);
    }
}

// ========================= FALLBACK (round-1, proven) =========================

__global__ __launch_bounds__(256) void fb_wconv(const float* __restrict__ Wx,
        const float* __restrict__ Wh, const float* __restrict__ Wa,
        half_t* __restrict__ WT) {
    __shared__ half_t tile[64][65];
    int bk = blockIdx.x % 40;
    int bn = blockIdx.x / 40;
    int k0 = bk * 64, n0 = bn * 64;
    #pragma unroll
    for (int i = 0; i < 16; ++i) {
        int idx = i * 256 + threadIdx.x;
        int r = idx >> 6, c = idx & 63;
        int k = k0 + r, n = n0 + c;
        float v;
        if (k < DD)            v = Wx[(size_t)k * 4096 + n];
        else if (k < DD + HH)  v = Wh[(size_t)(k - DD) * 4096 + n];
        else                   v = Wa[(size_t)(k - DD - HH) * 4096 + n];
        tile[c][r] = (half_t)v;
    }
    __syncthreads();
    #pragma unroll
    for (int i = 0; i < 16; ++i) {
        int idx = i * 256 + threadIdx.x;
        int r = idx >> 6, c = idx & 63;
        WT[(size_t)(n0 + r) * KFB + k0 + c] = tile[r][c];
    }
}

__global__ __launch_bounds__(256) void fb_init(const float* __restrict__ A,
        float* __restrict__ h0, float* __restrict__ c0) {
    int n = blockIdx.x;
    #pragma unroll
    for (int r = 0; r < 4; ++r) {
        int h = threadIdx.x + r * 256;
        const float4* ap = (const float4*)(A + ((size_t)n * HH + h) * 16);
        float s = 0.f;
        #pragma unroll
        for (int q = 0; q < 4; ++q) {
            float4 v = ap[q];
            s += v.x + v.y + v.z + v.w;
        }
        s *= (1.f / 16.f);
        h0[n * HH + h] = s;
        c0[n * HH + h] = s;
    }
}

__global__ __launch_bounds__(256) void fb_attn(const float* __restrict__ A,
        const float* __restrict__ hprev, long long hstride,
        half_t* __restrict__ h16, half_t* __restrict__ attn16) {
    __shared__ float sh[HH];
    __shared__ float sred[4][16];
    int n = blockIdx.x;
    const float* hp = hprev + (size_t)n * hstride;
    #pragma unroll
    for (int r = 0; r < 4; ++r) {
        int h = threadIdx.x + r * 256;
        float v = hp[h];
        sh[h] = v;
        h16[n * HH + h] = (half_t)v;
    }
    __syncthreads();
    float a[4][16];
    float ps[16];
    #pragma unroll
    for (int s = 0; s < 16; ++s) ps[s] = 0.f;
    #pragma unroll
    for (int r = 0; r < 4; ++r) {
        int h = threadIdx.x + r * 256;
        const float4* ap = (const float4*)(A + ((size_t)n * HH + h) * 16);
        float4 v0 = ap[0], v1 = ap[1], v2 = ap[2], v3 = ap[3];
        a[r][0] = v0.x;  a[r][1] = v0.y;  a[r][2]  = v0.z;  a[r][3]  = v0.w;
        a[r][4] = v1.x;  a[r][5] = v1.y;  a[r][6]  = v1.z;  a[r][7]  = v1.w;
        a[r][8] = v2.x;  a[r][9] = v2.y;  a[r][10] = v2.z;  a[r][11] = v2.w;
        a[r][12] = v3.x; a[r][13] = v3.y; a[r][14] = v3.z;  a[r][15] = v3.w;
        float hh = sh[h];
        #pragma unroll
        for (int s = 0; s < 16; ++s) ps[s] += hh * a[r][s];
    }
    #pragma unroll
    for (int off = 32; off; off >>= 1)
        #pragma unroll
        for (int s = 0; s < 16; ++s) ps[s] += __shfl_xor(ps[s], off, 64);
    int wave = threadIdx.x >> 6;
    if ((threadIdx.x & 63) == 0)
        #pragma unroll
        for (int s = 0; s < 16; ++s) sred[wave][s] = ps[s];
    __syncthreads();
    float sc[16], m = -1e30f;
    #pragma unroll
    for (int s = 0; s < 16; ++s) {
        sc[s] = (sred[0][s] + sred[1][s] + sred[2][s] + sred[3][s]) * 0.03125f;
        m = fmaxf(m, sc[s]);
    }
    float den = 0.f;
    #pragma unroll
    for (int s = 0; s < 16; ++s) { sc[s] = expf(sc[s] - m); den += sc[s]; }
    float inv = 1.f / den;
    #pragma unroll
    for (int r = 0; r < 4; ++r) {
        int h = threadIdx.x + r * 256;
        float acc = 0.f;
        #pragma unroll
        for (int s = 0; s < 16; ++s) acc += a[r][s] * sc[s];
        attn16[n * HH + h] = (half_t)(acc * inv);
    }
}

union LdsFB {
    struct {
        half_t sA[32][BK + 8];
        half_t sB[4][16][BK + 8];
    } s;
    float pe[4][32][16];
};

__global__ __launch_bounds__(256) void fb_gemm(const float* __restrict__ x,
        const half_t* __restrict__ h16, const half_t* __restrict__ attn16,
        const half_t* __restrict__ WT, const float* __restrict__ b,
        float* __restrict__ cbuf, float* __restrict__ out, int t) {
    __shared__ LdsFB L;
    int bid = blockIdx.x;
    int xcd = bid & 7;
    int slot = bid >> 3;
    int mtile = slot & 7;
    int jtile = slot >> 3;
    int m0 = mtile * 32;
    int j0 = xcd * 128 + jtile * 16;
    int tid = threadIdx.x;
    int wv = tid >> 6, lane = tid & 63;
    f32x4 acc[2] = {};
    int srA = tid >> 3, scA = (tid & 7) * 16;
    int srB = tid >> 2, scB = (tid & 3) * 32;
    int gB = srB >> 4, jcB = srB & 15;
    for (int it = 0; it < KFB / BK; ++it) {
        int k0 = it * BK;
        {
            int n = m0 + srA;
            if (k0 < DD) {
                const float* src = x + ((size_t)n * TT + t) * DD + k0 + scA;
                float4 v0 = ((const float4*)src)[0];
                float4 v1 = ((const float4*)src)[1];
                float4 v2 = ((const float4*)src)[2];
                float4 v3 = ((const float4*)src)[3];
                half8 p0, p1;
                p0[0] = (half_t)v0.x; p0[1] = (half_t)v0.y; p0[2] = (half_t)v0.z; p0[3] = (half_t)v0.w;
                p0[4] = (half_t)v1.x; p0[5] = (half_t)v1.y; p0[6] = (half_t)v1.z; p0[7] = (half_t)v1.w;
                p1[0] = (half_t)v2.x; p1[1] = (half_t)v2.y; p1[2] = (half_t)v2.z; p1[3] = (half_t)v2.w;
                p1[4] = (half_t)v3.x; p1[5] = (half_t)v3.y; p1[6] = (half_t)v3.z; p1[7] = (half_t)v3.w;
                *(half8*)&L.s.sA[srA][scA]     = p0;
                *(half8*)&L.s.sA[srA][scA + 8] = p1;
            } else {
                const half_t* srch = (k0 < DD + HH)
                    ? (h16    + (size_t)n * HH + (k0 - DD)      + scA)
                    : (attn16 + (size_t)n * HH + (k0 - DD - HH) + scA);
                uint4 u0 = ((const uint4*)srch)[0];
                uint4 u1 = ((const uint4*)srch)[1];
                *((uint4*)&L.s.sA[srA][scA])     = u0;
                *((uint4*)&L.s.sA[srA][scA + 8]) = u1;
            }
        }
        {
            const half_t* src = WT + ((size_t)(gB * HH + j0 + jcB)) * KFB + k0 + scB;
            uint4 u0 = ((const uint4*)src)[0];
            uint4 u1 = ((const uint4*)src)[1];
            uint4 u2 = ((const uint4*)src)[2];
            uint4 u3 = ((const uint4*)src)[3];
            *((uint4*)&L.s.sB[gB][jcB][scB])      = u0;
            *((uint4*)&L.s.sB[gB][jcB][scB + 8])  = u1;
            *((uint4*)&L.s.sB[gB][jcB][scB + 16]) = u2;
            *((uint4*)&L.s.sB[gB][jcB][scB + 24]) = u3;
        }
        __syncthreads();
        int row16 = lane & 15, kg = lane >> 4;
        #pragma unroll
        for (int kc = 0; kc < BK / 32; ++kc) {
            half8 bf = *(const half8*)&L.s.sB[wv][row16][kc * 32 + kg * 8];
            #pragma unroll
            for (int m = 0; m < 2; ++m) {
                half8 af = *(const half8*)&L.s.sA[row16 + m * 16][kc * 32 + kg * 8];
                acc[m] = __builtin_amdgcn_mfma_f32_16x16x32_f16(af, bf, acc[m], 0, 0, 0);
            }
        }
        __syncthreads();
    }
    {
        int col = lane & 15, rbase = (lane >> 4) * 4;
        #pragma unroll
        for (int m = 0; m < 2; ++m)
            #pragma unroll
            for (int q = 0; q < 4; ++q)
                L.pe[wv][m * 16 + rbase + q][col] = acc[m][q];
    }
    __syncthreads();
    #pragma unroll
    for (int q2 = 0; q2 < 2; ++q2) {
        int idx = tid + q2 * 256;
        int r = idx >> 4, jc = idx & 15;
        int n = m0 + r, j = j0 + jc;
        float vi = L.pe[0][r][jc] + b[j];
        float vf = L.pe[1][r][jc] + b[HH + j];
        float vo = L.pe[2][r][jc] + b[2 * HH + j];
        float vg = L.pe[3][r][jc] + b[3 * HH + j];
        float ig = 1.f / (1.f + expf(-vi));
        float fg = 1.f / (1.f + expf(-vf));
        float og = 1.f / (1.f + expf(-vo));
        float gg = tanhf(vg);
        size_t ci = (size_t)n * HH + j;
        float cp = cbuf[ci];
        float cn = fg * cp + ig * gg;
        cbuf[ci] = cn;
        out[((size_t)n * TT + t) * HH + j] = og * tanhf(cn);
    }
}

// ========================= HOST =========================

extern "C" void kernel_launch(void* const* d_in, const int* in_sizes, int n_in,
                              void* d_out, int out_size, void* d_ws, size_t ws_size,
                              hipStream_t stream) {
    const float* x  = (const float*)d_in[0];
    const float* A  = (const float*)d_in[1];
    const float* Wx = (const float*)d_in[2];
    const float* Wh = (const float*)d_in[3];
    const float* Wa = (const float*)d_in[4];
    const float* b  = (const float*)d_in[5];
    float* out = (float*)d_out;
    char* ws = (char*)d_ws;

    int maxb = 0;
    hipError_t oe = hipOccupancyMaxActiveBlocksPerMultiprocessor(&maxb, k_steps5, 512, 0);
    bool persistent_ok = (oe == hipSuccess && maxb >= 1);

    if (ws_size >= 375439616ULL && persistent_ok) {
        // fast path: XW-precompute + W-resident + direct-global-A persistent
        half_t* WhxT = (half_t*)(ws);                       // 12,582,912
        half_t* WaT  = (half_t*)(ws + 12582912);            //  8,388,608
        half_t* A16  = (half_t*)(ws + 20971520);            //  8,388,608
        half_t* AsT  = (half_t*)(ws + 29360128);            //  8,388,608 (freed after k_gemm_G)
        half_t* G16  = (half_t*)(ws + 37748736);            // 33,554,432
        half_t* h16a = (half_t*)(ws + 71303168);            //    524,288
        half_t* h16b = (half_t*)(ws + 71827456);            //    524,288
        float*  cb   = (float*) (ws + 72351744);            //  1,048,576
        half_t* x16  = (half_t*)(ws + 73449472);            // 33,554,432
        int*    bar  = (int*)   (ws + 107003904);           // 256 B (2 x 128 B half-domains)
        half_t* XW16 = (half_t*)(ws + 107004160);           // 268,435,456
        float*  sc0  = (float*)(ws + 29360128);             // 32,768 each (freed AsT region)
        float*  sc1  = (float*)(ws + 29360128 + 32768);
        float*  sc2  = (float*)(ws + 29360128 + 65536);

        hipLaunchKernelGGL(k_trans, dim3(8 * 64),  dim3(256), 0, stream, Wx, WhxT, KHX, 0,   8);
        hipLaunchKernelGGL(k_trans, dim3(16 * 64), dim3(256), 0, stream, Wh, WhxT, KHX, 512, 16);
        hipLaunchKernelGGL(k_trans, dim3(16 * 64), dim3(256), 0, stream, Wa, WaT,  HH,  0,   16);
        hipLaunchKernelGGL(k_convX, dim3(2048), dim3(256), 0, stream, x, x16);
        hipLaunchKernelGGL(k_convA2, dim3(256), dim3(256), 0, stream, A, A16, AsT, cb, h16a);
        hipLaunchKernelGGL(k_gemm_G, dim3(NB * 64), dim3(256), 0, stream, AsT, WaT, G16);
        hipLaunchKernelGGL(k_gemm_XW, dim3(256 * 64), dim3(256), 0, stream, x16, WhxT, XW16);
        hipLaunchKernelGGL(k_initsc, dim3(256), dim3(256), 0, stream, h16a, A16, sc0, sc1, sc2);
        hipMemsetAsync(bar, 0, 256, stream);
        hipLaunchKernelGGL(k_steps5, dim3(NBLK5), dim3(512), 0, stream,
                           XW16, h16a, h16b, WhxT, A16, G16, b, cb,
                           sc0, sc1, sc2, out, bar);
    } else if (ws_size >= 73449472ULL) {
        // round-2 mid path (proven)
        half_t* WhxT = (half_t*)(ws);
        half_t* WaT  = (half_t*)(ws + 12582912);
        half_t* A16  = (half_t*)(ws + 20971520);
        half_t* AsT  = (half_t*)(ws + 29360128);
        half_t* G16  = (half_t*)(ws + 37748736);
        half_t* h16a = (half_t*)(ws + 71303168);
        half_t* h16b = (half_t*)(ws + 71827456);
        float*  cb   = (float*) (ws + 72351744);
        float*  sc0  = (float*) (ws + 73400320);
        float*  sc1  = (float*) (ws + 73416704);
        float*  sc2  = (float*) (ws + 73433088);
        float* scb[3] = {sc0, sc1, sc2};

        hipLaunchKernelGGL(k_trans, dim3(8 * 64),  dim3(256), 0, stream, Wx, WhxT, KHX, 0,   8);
        hipLaunchKernelGGL(k_trans, dim3(16 * 64), dim3(256), 0, stream, Wh, WhxT, KHX, 512, 16);
        hipLaunchKernelGGL(k_trans, dim3(16 * 64), dim3(256), 0, stream, Wa, WaT,  HH,  0,   16);
        hipLaunchKernelGGL(k_convA, dim3(256), dim3(256), 0, stream,
                           A, A16, AsT, cb, h16a, sc0, sc1, sc2);
        hipLaunchKernelGGL(k_gemm_G, dim3(NB * 64), dim3(256), 0, stream, AsT, WaT, G16);
        for (int t = 0; t < TT; ++t) {
            float* scC = scb[t % 3];
            float* scN = scb[(t + 1) % 3];
            float* scZ = scb[(t + 2) % 3];
            half_t* h16c = (t & 1) ? h16b : h16a;
            half_t* h16n = (t & 1) ? h16a : h16b;
            hipLaunchKernelGGL(k_step, dim3(512), dim3(256), 0, stream,
                               x, h16c, h16n, WhxT, A16, G16, b, cb, scC, scN, scZ, out, t);
        }
    } else {
        // round-1 fallback (24.1 MB)
        half_t* WT  = (half_t*)ws;
        float*  h0  = (float*)(ws + 20971520);
        float*  cb  = (float*)(ws + 22020096);
        half_t* h16 = (half_t*)(ws + 23068672);
        half_t* a16 = (half_t*)(ws + 23592960);
        hipLaunchKernelGGL(fb_wconv, dim3(2560), dim3(256), 0, stream, Wx, Wh, Wa, WT);
        hipLaunchKernelGGL(fb_init, dim3(256), dim3(256), 0, stream, A, h0, cb);
        for (int t = 0; t < TT; ++t) {
            const float* hp = (t == 0) ? h0 : (out + (size_t)(t - 1) * HH);
            long long hstride = (t == 0) ? (long long)HH : (long long)TT * HH;
            hipLaunchKernelGGL(fb_attn, dim3(256), dim3(256), 0, stream, A, hp, hstride, h16, a16);
            hipLaunchKernelGGL(fb_gemm, dim3(512), dim3(256), 0, stream,
                               x, h16, a16, WT, b, cb, out, t);
        }
    }
}